// Round 2
// baseline (732.869 us; speedup 1.0000x reference)
//
#include <hip/hip_runtime.h>
#include <hip/hip_bf16.h>

#define PI_F 3.14159265358979323846f

__device__ __forceinline__ float fast_tanh(float x) {
    // tanh(x) = 1 - 2/(exp(2x)+1); graceful at +/-inf
    float e = __expf(2.0f * x);
    return 1.0f - 2.0f / (e + 1.0f);
}

// ---------------- K0: pre-transpose small weight matrices into ws ----------------
// wt layout: [6 mats][2 depths][64 c][64 k], Bt[c][k] = W[k][c]
__global__ void k_prep_wt(const float* __restrict__ pp_w1,
                          const float* __restrict__ pp_w2,
                          const float* __restrict__ pi_w1,
                          const float* __restrict__ ii_w1,
                          const float* __restrict__ ii_w2,
                          float* __restrict__ wt) {
    int idx = blockIdx.x * blockDim.x + threadIdx.x;
    if (idx >= 6 * 2 * 4096) return;
    int k = idx & 63;
    int c = (idx >> 6) & 63;
    int d = (idx >> 12) & 1;
    int m = idx >> 13;
    float val = 0.f;
    switch (m) {
        case 0: val = pp_w1[d * 4096 + k * 64 + c]; break;                 // pp_w1^T
        case 1: val = pp_w2[d * 4096 + k * 64 + c]; break;                 // pp_w2^T
        case 2: val = pi_w1[d * 8192 + k * 64 + c]; break;                 // pi_w1 top^T
        case 3: val = pi_w1[d * 8192 + (64 + k) * 64 + c]; break;          // pi_w1 bot^T
        case 4: val = ii_w1[d * 4096 + k * 64 + c]; break;                 // ii_w1^T
        case 5: val = ii_w2[d * 12288 + k * 192 + c]; break;               // ii_w2[:, :64]^T
    }
    wt[idx] = val;
}

// ---------------- K1: pair geometry -> RBF basis [P,16] ----------------
__global__ void k_pairprep(const float* __restrict__ pair_diff,
                           float* __restrict__ basis, int P) {
    int p = blockIdx.x * blockDim.x + threadIdx.x;
    if (p >= P) return;
    float x = pair_diff[3 * p + 0];
    float y = pair_diff[3 * p + 1];
    float z = pair_diff[3 * p + 2];
    float d = sqrtf(x * x + y * y + z * z + 1e-12f);
    float fc = 0.0f;
    if (d < 4.0f) fc = 0.5f * (__cosf(PI_F * d * 0.25f) + 1.0f);
    const float inv_sigma = 15.0f / 4.0f;
    float out[16];
    #pragma unroll
    for (int b = 0; b < 16; ++b) {
        float cb = (4.0f / 15.0f) * (float)b;
        float tt = (d - cb) * inv_sigma;
        out[b] = __expf(-0.5f * tt * tt) * fc;
    }
    float4* o4 = (float4*)(basis + (size_t)p * 16);
    o4[0] = make_float4(out[0], out[1], out[2], out[3]);
    o4[1] = make_float4(out[4], out[5], out[6], out[7]);
    o4[2] = make_float4(out[8], out[9], out[10], out[11]);
    o4[3] = make_float4(out[12], out[13], out[14], out[15]);
}

// ---------------- K2: embedding gather p1 = embed_w[Z] ----------------
__global__ void k_embed(const int* __restrict__ Z, const float* __restrict__ embed_w,
                        float* __restrict__ p1, int N) {
    int idx = blockIdx.x * blockDim.x + threadIdx.x;
    if (idx >= N * 64) return;
    int n = idx >> 6, c = idx & 63;
    p1[idx] = embed_w[Z[n] * 64 + c];
}

// ---------------- shared GEMM helper: C[64x64] = A[64x64(pad68)] @ Bt^T ----------------
// Bt is [64][64] row-major with Bt[c][k] = B[k][c]; thread (tx,ty) owns rows ty+16i, cols tx+16j
__device__ __forceinline__ void gemm64(const float (*A)[68], const float* __restrict__ Bt,
                                       int tx, int ty, float acc[4][4]) {
    #pragma unroll
    for (int i = 0; i < 4; ++i)
        #pragma unroll
        for (int j = 0; j < 4; ++j) acc[i][j] = 0.f;
    #pragma unroll 8
    for (int k = 0; k < 64; k += 2) {
        float2 bv[4];
        #pragma unroll
        for (int j = 0; j < 4; ++j)
            bv[j] = *(const float2*)(Bt + (tx + 16 * j) * 64 + k);
        #pragma unroll
        for (int i = 0; i < 4; ++i) {
            float2 av = *(const float2*)&A[ty + 16 * i][k];
            #pragma unroll
            for (int j = 0; j < 4; ++j)
                acc[i][j] = fmaf(av.x, bv[j].x, fmaf(av.y, bv[j].y, acc[i][j]));
        }
    }
}

// ---------------- K3: per-atom pp MLP + u/v precompute ----------------
// h = tanh(tanh(p1@W1+b1)@W2+b2); u = h@pi_w1_top + pi_b1; v = h@pi_w1_bot
__launch_bounds__(256, 2)
__global__ void k_pp(const float* __restrict__ p1,
                     const float* __restrict__ w1t, const float* __restrict__ b1,
                     const float* __restrict__ w2t, const float* __restrict__ b2,
                     const float* __restrict__ wut, const float* __restrict__ wvt,
                     const float* __restrict__ bu,
                     float* __restrict__ u, float* __restrict__ v, int N) {
    __shared__ float sA[64][68];
    __shared__ float sH[64][68];
    int t = threadIdx.x;
    int a0 = blockIdx.x * 64;
    {
        int r = t >> 2, q = t & 3;
        int a = a0 + r;
        #pragma unroll
        for (int w = 0; w < 4; ++w) {
            int cc = q * 16 + w * 4;
            float4 val = make_float4(0.f, 0.f, 0.f, 0.f);
            if (a < N) val = *(const float4*)(p1 + (size_t)a * 64 + cc);
            *(float4*)&sA[r][cc] = val;
        }
    }
    __syncthreads();
    const int tx = t >> 4, ty = t & 15;

    float acc[4][4];
    gemm64(sA, w1t, tx, ty, acc);          // layer 1
    #pragma unroll
    for (int i = 0; i < 4; ++i)
        #pragma unroll
        for (int j = 0; j < 4; ++j)
            sH[ty + 16 * i][tx + 16 * j] = fast_tanh(acc[i][j] + b1[tx + 16 * j]);
    __syncthreads();                       // sH ready; sA reads done
    gemm64(sH, w2t, tx, ty, acc);          // layer 2
    #pragma unroll
    for (int i = 0; i < 4; ++i)
        #pragma unroll
        for (int j = 0; j < 4; ++j)
            sA[ty + 16 * i][tx + 16 * j] = fast_tanh(acc[i][j] + b2[tx + 16 * j]);
    __syncthreads();                       // sA now holds h

    float accU[4][4], accV[4][4];
    gemm64(sA, wut, tx, ty, accU);
    gemm64(sA, wvt, tx, ty, accV);
    #pragma unroll
    for (int i = 0; i < 4; ++i) {
        int a = a0 + ty + 16 * i;
        if (a < N) {
            #pragma unroll
            for (int j = 0; j < 4; ++j) {
                int c = tx + 16 * j;
                u[(size_t)a * 64 + c] = accU[i][j] + bu[c];
                v[(size_t)a * 64 + c] = accV[i][j];
            }
        }
    }
}

// ---------------- K4: fused pair kernel (dominant) ----------------
// per pair: g=tanh(u[i]+v[j]); i1[c]=sum_b tanh(g@w2 + b2)[c*16+b]*basis[b];
// i1a = tanh(i1@ii_w1) @ ii_w2[:, :64]; atomic scatter p1[pair_i] += i1a
__launch_bounds__(256, 2)
__global__ void k_pair(const float* __restrict__ u, const float* __restrict__ v,
                       const int* __restrict__ pair_i, const int* __restrict__ pair_j,
                       const float* __restrict__ basis,
                       const float* __restrict__ w2, const float* __restrict__ b2,
                       const float* __restrict__ w3t, const float* __restrict__ w4t,
                       float* __restrict__ p1, int P) {
    __shared__ float sG[64][68];
    __shared__ float sI1[64][68];
    __shared__ float sH[64][68];
    __shared__ float sB[64][20];
    __shared__ int sPi[64];

    int t = threadIdx.x;
    int base = blockIdx.x * 64;
    {
        int r = t >> 2, q = t & 3;
        int p = base + r;
        bool valid = (p < P);
        int ai = 0, aj = 0;
        if (valid) { ai = pair_i[p]; aj = pair_j[p]; }
        if (q == 0) sPi[r] = valid ? ai : -1;
        #pragma unroll
        for (int w = 0; w < 4; ++w) {
            int cc = q * 16 + w * 4;
            float4 g4 = make_float4(0.f, 0.f, 0.f, 0.f);
            if (valid) {
                float4 uu = *(const float4*)(u + (size_t)ai * 64 + cc);
                float4 vv = *(const float4*)(v + (size_t)aj * 64 + cc);
                g4.x = fast_tanh(uu.x + vv.x);
                g4.y = fast_tanh(uu.y + vv.y);
                g4.z = fast_tanh(uu.z + vv.z);
                g4.w = fast_tanh(uu.w + vv.w);
            }
            *(float4*)&sG[r][cc] = g4;
        }
        float4 b4 = make_float4(0.f, 0.f, 0.f, 0.f);
        if (valid) b4 = *(const float4*)(basis + (size_t)p * 16 + q * 4);
        *(float4*)&sB[r][q * 4] = b4;
    }
    __syncthreads();
    const int tx = t >> 4, ty = t & 15;

    // big fused GEMM over n = c*16+b, in 4 chunks of 256 columns
    #pragma unroll 1
    for (int chunk = 0; chunk < 4; ++chunk) {
        float acc[4][16];
        #pragma unroll
        for (int i = 0; i < 4; ++i)
            #pragma unroll
            for (int n = 0; n < 16; ++n) acc[i][n] = 0.f;
        const float* wrow = w2 + chunk * 256 + tx * 16;
        #pragma unroll 4
        for (int k = 0; k < 64; ++k) {
            const float* wk = wrow + (size_t)k * 1024;
            float4 w4a = *(const float4*)(wk);
            float4 w4b = *(const float4*)(wk + 4);
            float4 w4c = *(const float4*)(wk + 8);
            float4 w4d = *(const float4*)(wk + 12);
            float wv[16] = {w4a.x, w4a.y, w4a.z, w4a.w,
                            w4b.x, w4b.y, w4b.z, w4b.w,
                            w4c.x, w4c.y, w4c.z, w4c.w,
                            w4d.x, w4d.y, w4d.z, w4d.w};
            #pragma unroll
            for (int i = 0; i < 4; ++i) {
                float a = sG[ty + 16 * i][k];
                #pragma unroll
                for (int n = 0; n < 16; ++n)
                    acc[i][n] = fmaf(a, wv[n], acc[i][n]);
            }
        }
        int cc = chunk * 16 + tx;
        const float* bp = b2 + cc * 16;
        float4 bb0 = *(const float4*)(bp);
        float4 bb1 = *(const float4*)(bp + 4);
        float4 bb2 = *(const float4*)(bp + 8);
        float4 bb3 = *(const float4*)(bp + 12);
        float bv[16] = {bb0.x, bb0.y, bb0.z, bb0.w,
                        bb1.x, bb1.y, bb1.z, bb1.w,
                        bb2.x, bb2.y, bb2.z, bb2.w,
                        bb3.x, bb3.y, bb3.z, bb3.w};
        #pragma unroll
        for (int i = 0; i < 4; ++i) {
            int pr = ty + 16 * i;
            float s = 0.f;
            #pragma unroll
            for (int b = 0; b < 16; ++b)
                s += fast_tanh(acc[i][b] + bv[b]) * sB[pr][b];
            sI1[pr][cc] = s;
        }
    }
    __syncthreads();

    float acc3[4][4];
    gemm64(sI1, w3t, tx, ty, acc3);        // i1 @ ii_w1
    #pragma unroll
    for (int i = 0; i < 4; ++i)
        #pragma unroll
        for (int j = 0; j < 4; ++j)
            sH[ty + 16 * i][tx + 16 * j] = fast_tanh(acc3[i][j]);
    __syncthreads();
    gemm64(sH, w4t, tx, ty, acc3);         // @ ii_w2[:, :64]
    #pragma unroll
    for (int i = 0; i < 4; ++i) {
        int ai = sPi[ty + 16 * i];
        if (ai >= 0) {
            #pragma unroll
            for (int j = 0; j < 4; ++j)
                atomicAdd(p1 + (size_t)ai * 64 + tx + 16 * j, acc3[i][j]);
        }
    }
}

// ---------------- K5: readout + batch segment sum ----------------
__global__ void k_readout(const float* __restrict__ p1, const float* __restrict__ rw1,
                          const float* __restrict__ rb1, const float* __restrict__ rw2,
                          const float* __restrict__ rb2, const int* __restrict__ abatch,
                          float* __restrict__ out, int N) {
    int t = threadIdx.x;
    int a = blockIdx.x * 8 + (t >> 5);
    int c = t & 31;
    if (a >= N) return;
    float acc = rb1[c];
    const float* pr = p1 + (size_t)a * 64;
    #pragma unroll
    for (int k = 0; k < 64; ++k)
        acc = fmaf(pr[k], rw1[k * 32 + c], acc);
    float e = fast_tanh(acc) * rw2[c];
    #pragma unroll
    for (int off = 16; off > 0; off >>= 1)
        e += __shfl_down(e, off, 32);
    if (c == 0) atomicAdd(&out[abatch[a]], e + rb2[0]);
}

extern "C" void kernel_launch(void* const* d_in, const int* in_sizes, int n_in,
                              void* d_out, int out_size, void* d_ws, size_t ws_size,
                              hipStream_t stream) {
    const int*   Z         = (const int*)  d_in[0];
    const float* pair_diff = (const float*)d_in[1];
    const int*   pair_i    = (const int*)  d_in[2];
    const int*   pair_j    = (const int*)  d_in[3];
    const int*   abatch    = (const int*)  d_in[4];
    // d_in[5] = n_mol scalar (== out_size)
    const float* embed_w   = (const float*)d_in[6];
    const float* pp_w1     = (const float*)d_in[7];
    const float* pp_b1     = (const float*)d_in[8];
    const float* pp_w2     = (const float*)d_in[9];
    const float* pp_b2     = (const float*)d_in[10];
    const float* pi_w1     = (const float*)d_in[11];
    const float* pi_b1     = (const float*)d_in[12];
    const float* pi_w2     = (const float*)d_in[13];
    const float* pi_b2     = (const float*)d_in[14];
    const float* ii_w1     = (const float*)d_in[15];
    const float* ii_w2     = (const float*)d_in[16];
    // d_in[17] = pix_w : dead w.r.t. delta_energy (p3 never feeds the readout)
    const float* ro_w1     = (const float*)d_in[18];
    const float* ro_b1     = (const float*)d_in[19];
    const float* ro_w2     = (const float*)d_in[20];
    const float* ro_b2     = (const float*)d_in[21];

    const int N = in_sizes[0];
    const int P = in_sizes[2];

    float* ws    = (float*)d_ws;
    float* basis = ws;                          // P*16
    float* p1    = basis + (size_t)P * 16;      // N*64
    float* u     = p1 + (size_t)N * 64;         // N*64
    float* v     = u + (size_t)N * 64;          // N*64
    float* wt    = v + (size_t)N * 64;          // 6*2*4096

    float* out_f = (float*)d_out;
    (void)hipMemsetAsync(d_out, 0, (size_t)out_size * sizeof(float), stream);

    k_prep_wt<<<(6 * 2 * 4096 + 255) / 256, 256, 0, stream>>>(pp_w1, pp_w2, pi_w1, ii_w1, ii_w2, wt);
    k_pairprep<<<(P + 255) / 256, 256, 0, stream>>>(pair_diff, basis, P);
    k_embed<<<(N * 64 + 255) / 256, 256, 0, stream>>>(Z, embed_w, p1, N);

    for (int d = 0; d < 2; ++d) {
        const float* ppw1t = wt + (0 * 2 + d) * 4096;
        const float* ppw2t = wt + (1 * 2 + d) * 4096;
        const float* pi1tt = wt + (2 * 2 + d) * 4096;
        const float* pi1tb = wt + (3 * 2 + d) * 4096;
        const float* w3t   = wt + (4 * 2 + d) * 4096;
        const float* w4t   = wt + (5 * 2 + d) * 4096;
        k_pp<<<(N + 63) / 64, 256, 0, stream>>>(p1, ppw1t, pp_b1 + d * 64, ppw2t, pp_b2 + d * 64,
                                                pi1tt, pi1tb, pi_b1 + d * 64, u, v, N);
        k_pair<<<(P + 63) / 64, 256, 0, stream>>>(u, v, pair_i, pair_j, basis,
                                                  pi_w2 + (size_t)d * 65536, pi_b2 + d * 1024,
                                                  w3t, w4t, p1, P);
    }

    k_readout<<<(N + 7) / 8, 256, 0, stream>>>(p1, ro_w1, ro_b1, ro_w2, ro_b2, abatch, out_f, N);
}

// Round 3
// 273.949 us; speedup vs baseline: 2.6752x; 2.6752x over previous
//
#include <hip/hip_runtime.h>
#include <hip/hip_bf16.h>

#define PI_F 3.14159265358979323846f

typedef __bf16 bf16x8 __attribute__((ext_vector_type(8)));
typedef float  f32x4  __attribute__((ext_vector_type(4)));

#define MFMA16(a, b, c) __builtin_amdgcn_mfma_f32_16x16x32_bf16((a), (b), (c), 0, 0, 0)

__device__ __forceinline__ float fast_tanh(float x) {
    float e = __expf(2.0f * x);
    return 1.0f - 2.0f * __fdividef(1.0f, e + 1.0f);
}

// ---------------- K0: fp32 transposes for k_pp ----------------
// wt layout: [4 mats][2 depths][64 c][64 k], Bt[c][k] = W[k][c]
__global__ void k_prep_wt(const float* __restrict__ pp_w1,
                          const float* __restrict__ pp_w2,
                          const float* __restrict__ pi_w1,
                          float* __restrict__ wt) {
    int idx = blockIdx.x * blockDim.x + threadIdx.x;
    if (idx >= 4 * 2 * 4096) return;
    int k = idx & 63;
    int c = (idx >> 6) & 63;
    int d = (idx >> 12) & 1;
    int m = idx >> 13;
    float val = 0.f;
    switch (m) {
        case 0: val = pp_w1[d * 4096 + k * 64 + c]; break;
        case 1: val = pp_w2[d * 4096 + k * 64 + c]; break;
        case 2: val = pi_w1[d * 8192 + k * 64 + c]; break;          // top half
        case 3: val = pi_w1[d * 8192 + (64 + k) * 64 + c]; break;   // bottom half
    }
    wt[idx] = val;
}

// ---------------- K0b: bf16 transposed weight copies for MFMA ----------------
// w2bf[d][n][k] = pi_w2[d][k][n]   (n<1024, k<64)
// w3bf[d][n][k] = ii_w1[d][k][n]   (64x64)
// w4bf[d][n][k] = ii_w2[d][k][n]   (first 64 cols of 192)
__global__ void k_prep_bf(const float* __restrict__ pi_w2,
                          const float* __restrict__ ii_w1,
                          const float* __restrict__ ii_w2,
                          __bf16* __restrict__ w2bf,
                          __bf16* __restrict__ w3bf,
                          __bf16* __restrict__ w4bf) {
    int idx = blockIdx.x * blockDim.x + threadIdx.x;
    if (idx < 131072) {
        int d = idx >> 16, r = idx & 65535;
        int n = r >> 6, k = r & 63;
        w2bf[idx] = (__bf16)pi_w2[d * 65536 + k * 1024 + n];
    } else if (idx < 139264) {
        int tt = idx - 131072;
        int d = tt >> 12, r = tt & 4095;
        int n = r >> 6, k = r & 63;
        w3bf[tt] = (__bf16)ii_w1[d * 4096 + k * 64 + n];
    } else if (idx < 147456) {
        int tt = idx - 139264;
        int d = tt >> 12, r = tt & 4095;
        int n = r >> 6, k = r & 63;
        w4bf[tt] = (__bf16)ii_w2[d * 12288 + k * 192 + n];
    }
}

// ---------------- K1: pair geometry -> RBF basis [P,16] ----------------
__global__ void k_pairprep(const float* __restrict__ pair_diff,
                           float* __restrict__ basis, int P) {
    int p = blockIdx.x * blockDim.x + threadIdx.x;
    if (p >= P) return;
    float x = pair_diff[3 * p + 0];
    float y = pair_diff[3 * p + 1];
    float z = pair_diff[3 * p + 2];
    float d = sqrtf(x * x + y * y + z * z + 1e-12f);
    float fc = 0.0f;
    if (d < 4.0f) fc = 0.5f * (__cosf(PI_F * d * 0.25f) + 1.0f);
    const float inv_sigma = 15.0f / 4.0f;
    float out[16];
    #pragma unroll
    for (int b = 0; b < 16; ++b) {
        float cb = (4.0f / 15.0f) * (float)b;
        float tt = (d - cb) * inv_sigma;
        out[b] = __expf(-0.5f * tt * tt) * fc;
    }
    float4* o4 = (float4*)(basis + (size_t)p * 16);
    o4[0] = make_float4(out[0], out[1], out[2], out[3]);
    o4[1] = make_float4(out[4], out[5], out[6], out[7]);
    o4[2] = make_float4(out[8], out[9], out[10], out[11]);
    o4[3] = make_float4(out[12], out[13], out[14], out[15]);
}

// ---------------- K2: embedding gather ----------------
__global__ void k_embed(const int* __restrict__ Z, const float* __restrict__ embed_w,
                        float* __restrict__ p1, int N) {
    int idx = blockIdx.x * blockDim.x + threadIdx.x;
    if (idx >= N * 64) return;
    int n = idx >> 6, c = idx & 63;
    p1[idx] = embed_w[Z[n] * 64 + c];
}

// ---------------- fp32 64x64 GEMM helper (k_pp only) ----------------
__device__ __forceinline__ void gemm64(const float (*A)[68], const float* __restrict__ Bt,
                                       int tx, int ty, float acc[4][4]) {
    #pragma unroll
    for (int i = 0; i < 4; ++i)
        #pragma unroll
        for (int j = 0; j < 4; ++j) acc[i][j] = 0.f;
    #pragma unroll 8
    for (int k = 0; k < 64; k += 2) {
        float2 bv[4];
        #pragma unroll
        for (int j = 0; j < 4; ++j)
            bv[j] = *(const float2*)(Bt + (tx + 16 * j) * 64 + k);
        #pragma unroll
        for (int i = 0; i < 4; ++i) {
            float2 av = *(const float2*)&A[ty + 16 * i][k];
            #pragma unroll
            for (int j = 0; j < 4; ++j)
                acc[i][j] = fmaf(av.x, bv[j].x, fmaf(av.y, bv[j].y, acc[i][j]));
        }
    }
}

// ---------------- K3: per-atom pp MLP + u/v precompute (fp32) ----------------
__launch_bounds__(256, 2)
__global__ void k_pp(const float* __restrict__ p1,
                     const float* __restrict__ w1t, const float* __restrict__ b1,
                     const float* __restrict__ w2t, const float* __restrict__ b2,
                     const float* __restrict__ wut, const float* __restrict__ wvt,
                     const float* __restrict__ bu,
                     float* __restrict__ u, float* __restrict__ v, int N) {
    __shared__ float sA[64][68];
    __shared__ float sH[64][68];
    int t = threadIdx.x;
    int a0 = blockIdx.x * 64;
    {
        int r = t >> 2, q = t & 3;
        int a = a0 + r;
        #pragma unroll
        for (int w = 0; w < 4; ++w) {
            int cc = q * 16 + w * 4;
            float4 val = make_float4(0.f, 0.f, 0.f, 0.f);
            if (a < N) val = *(const float4*)(p1 + (size_t)a * 64 + cc);
            *(float4*)&sA[r][cc] = val;
        }
    }
    __syncthreads();
    const int tx = t >> 4, ty = t & 15;

    float acc[4][4];
    gemm64(sA, w1t, tx, ty, acc);
    #pragma unroll
    for (int i = 0; i < 4; ++i)
        #pragma unroll
        for (int j = 0; j < 4; ++j)
            sH[ty + 16 * i][tx + 16 * j] = fast_tanh(acc[i][j] + b1[tx + 16 * j]);
    __syncthreads();
    gemm64(sH, w2t, tx, ty, acc);
    #pragma unroll
    for (int i = 0; i < 4; ++i)
        #pragma unroll
        for (int j = 0; j < 4; ++j)
            sA[ty + 16 * i][tx + 16 * j] = fast_tanh(acc[i][j] + b2[tx + 16 * j]);
    __syncthreads();

    float accU[4][4], accV[4][4];
    gemm64(sA, wut, tx, ty, accU);
    gemm64(sA, wvt, tx, ty, accV);
    #pragma unroll
    for (int i = 0; i < 4; ++i) {
        int a = a0 + ty + 16 * i;
        if (a < N) {
            #pragma unroll
            for (int j = 0; j < 4; ++j) {
                int c = tx + 16 * j;
                u[(size_t)a * 64 + c] = accU[i][j] + bu[c];
                v[(size_t)a * 64 + c] = accV[i][j];
            }
        }
    }
}

// ---------------- K4: fused pair kernel — bf16 MFMA ----------------
// S = g @ w2 computed transposed: D[n][pair] via A=w2^T (global bf16), B=g^T (LDS frags).
// C/D layout (16x16x32): row=(lane>>4)*4+reg, col=lane&15  => row=n (c=n>>4,b=n&15), col=pair.
__launch_bounds__(256, 2)
__global__ void k_pair(const float* __restrict__ u, const float* __restrict__ v,
                       const int* __restrict__ pair_i, const int* __restrict__ pair_j,
                       const float* __restrict__ basis,
                       const __bf16* __restrict__ w2bf, const float* __restrict__ b2,
                       const __bf16* __restrict__ w3bf, const __bf16* __restrict__ w4bf,
                       float* __restrict__ p1, int P) {
    __shared__ __bf16 sG[64][72];    // g  [pair][k], pad 72 => <=2-way LDS conflicts
    __shared__ __bf16 sI1[64][72];   // i1 [pair][c]
    __shared__ __bf16 sHh[64][72];   // h  [pair][o]
    __shared__ float sB[64][20];     // basis [pair][16]
    __shared__ int sPi[64];

    const int t = threadIdx.x;
    const int base = blockIdx.x * 64;

    // ---- phase 1: g = tanh(u[i]+v[j]) -> bf16 LDS; basis -> LDS ----
    {
        int r = t >> 2, q = t & 3;
        int p = base + r;
        bool valid = (p < P);
        int ai = 0, aj = 0;
        if (valid) { ai = pair_i[p]; aj = pair_j[p]; }
        if (q == 0) sPi[r] = valid ? ai : -1;
        int cc = q * 16;
        bf16x8 g8a, g8b;
        f32x4 b4 = {0.f, 0.f, 0.f, 0.f};
        if (valid) {
            const f32x4* up = (const f32x4*)(u + (size_t)ai * 64 + cc);
            const f32x4* vp = (const f32x4*)(v + (size_t)aj * 64 + cc);
            f32x4 u0 = up[0], u1 = up[1], u2 = up[2], u3 = up[3];
            f32x4 v0 = vp[0], v1 = vp[1], v2 = vp[2], v3 = vp[3];
            #pragma unroll
            for (int e = 0; e < 4; ++e) {
                g8a[e]     = (__bf16)fast_tanh(u0[e] + v0[e]);
                g8a[4 + e] = (__bf16)fast_tanh(u1[e] + v1[e]);
                g8b[e]     = (__bf16)fast_tanh(u2[e] + v2[e]);
                g8b[4 + e] = (__bf16)fast_tanh(u3[e] + v3[e]);
            }
            b4 = *(const f32x4*)(basis + (size_t)p * 16 + q * 4);
        } else {
            #pragma unroll
            for (int e = 0; e < 8; ++e) { g8a[e] = (__bf16)0.f; g8b[e] = (__bf16)0.f; }
        }
        *(bf16x8*)&sG[r][cc]     = g8a;
        *(bf16x8*)&sG[r][cc + 8] = g8b;
        *(f32x4*)&sB[r][q * 4]   = b4;
    }
    __syncthreads();

    const int l  = t & 63;
    const int wv = t >> 6;
    const int ll = l & 15;
    const int lg = l >> 4;

    // B-frags: g^T, kept in registers for the whole main loop
    bf16x8 bg[4][2];
    #pragma unroll
    for (int pt = 0; pt < 4; ++pt)
        #pragma unroll
        for (int kt = 0; kt < 2; ++kt)
            bg[pt][kt] = *(const bf16x8*)&sG[pt * 16 + ll][kt * 32 + lg * 8];

    // ---- main loop: wave wv owns n in [wv*256, wv*256+256) => c in [wv*16, wv*16+16) ----
    #pragma unroll 1
    for (int mc = 0; mc < 4; ++mc) {
        f32x4 acc[4][4];   // [mt][pt]
        const f32x4 z4 = {0.f, 0.f, 0.f, 0.f};
        #pragma unroll
        for (int mt = 0; mt < 4; ++mt)
            #pragma unroll
            for (int pt = 0; pt < 4; ++pt) acc[mt][pt] = z4;

        #pragma unroll
        for (int mt = 0; mt < 4; ++mt) {
            const __bf16* ar = w2bf + (size_t)(wv * 256 + mc * 64 + mt * 16 + ll) * 64 + lg * 8;
            bf16x8 a0 = *(const bf16x8*)(ar);
            bf16x8 a1 = *(const bf16x8*)(ar + 32);
            #pragma unroll
            for (int pt = 0; pt < 4; ++pt) {
                acc[mt][pt] = MFMA16(a0, bg[pt][0], acc[mt][pt]);
                acc[mt][pt] = MFMA16(a1, bg[pt][1], acc[mt][pt]);
            }
        }
        // epilogue: i1[p][c] = sum_b tanh(S + b2) * basis[p][b]; b = lg*4+reg, p = pt*16+ll
        #pragma unroll
        for (int mt = 0; mt < 4; ++mt) {
            int c = wv * 16 + mc * 4 + mt;
            f32x4 bias = *(const f32x4*)(b2 + c * 16 + lg * 4);
            #pragma unroll
            for (int pt = 0; pt < 4; ++pt) {
                f32x4 bas = *(const f32x4*)&sB[pt * 16 + ll][lg * 4];
                float s = 0.f;
                #pragma unroll
                for (int r = 0; r < 4; ++r)
                    s = fmaf(fast_tanh(acc[mt][pt][r] + bias[r]), bas[r], s);
                s += __shfl_xor(s, 16);
                s += __shfl_xor(s, 32);
                if (l < 16) sI1[pt * 16 + ll][c] = (__bf16)s;
            }
        }
    }
    __syncthreads();

    // ---- ii GEMM1: t = i1 @ ii_w1 ; wave wv owns out cols [wv*16, wv*16+16) ----
    f32x4 acc2[4];
    {
        const f32x4 z4 = {0.f, 0.f, 0.f, 0.f};
        #pragma unroll
        for (int mt = 0; mt < 4; ++mt) acc2[mt] = z4;
    }
    #pragma unroll
    for (int kt = 0; kt < 2; ++kt) {
        bf16x8 bw = *(const bf16x8*)(w3bf + (size_t)(wv * 16 + ll) * 64 + kt * 32 + lg * 8);
        #pragma unroll
        for (int mt = 0; mt < 4; ++mt) {
            bf16x8 af = *(const bf16x8*)&sI1[mt * 16 + ll][kt * 32 + lg * 8];
            acc2[mt] = MFMA16(af, bw, acc2[mt]);
        }
    }
    #pragma unroll
    for (int mt = 0; mt < 4; ++mt)
        #pragma unroll
        for (int r = 0; r < 4; ++r)
            sHh[mt * 16 + lg * 4 + r][wv * 16 + ll] = (__bf16)fast_tanh(acc2[mt][r]);
    __syncthreads();

    // ---- ii GEMM2: i1a = h @ ii_w2[:, :64] ; scatter atomicAdd to p1[pair_i] ----
    f32x4 acc3[4];
    {
        const f32x4 z4 = {0.f, 0.f, 0.f, 0.f};
        #pragma unroll
        for (int mt = 0; mt < 4; ++mt) acc3[mt] = z4;
    }
    #pragma unroll
    for (int kt = 0; kt < 2; ++kt) {
        bf16x8 bw = *(const bf16x8*)(w4bf + (size_t)(wv * 16 + ll) * 64 + kt * 32 + lg * 8);
        #pragma unroll
        for (int mt = 0; mt < 4; ++mt) {
            bf16x8 af = *(const bf16x8*)&sHh[mt * 16 + ll][kt * 32 + lg * 8];
            acc3[mt] = MFMA16(af, bw, acc3[mt]);
        }
    }
    #pragma unroll
    for (int mt = 0; mt < 4; ++mt) {
        #pragma unroll
        for (int r = 0; r < 4; ++r) {
            int p = mt * 16 + lg * 4 + r;
            int ai = sPi[p];
            if (ai >= 0)
                atomicAdd(p1 + (size_t)ai * 64 + wv * 16 + ll, acc3[mt][r]);
        }
    }
}

// ---------------- K5: readout + batch segment sum ----------------
__global__ void k_readout(const float* __restrict__ p1, const float* __restrict__ rw1,
                          const float* __restrict__ rb1, const float* __restrict__ rw2,
                          const float* __restrict__ rb2, const int* __restrict__ abatch,
                          float* __restrict__ out, int N) {
    int t = threadIdx.x;
    int a = blockIdx.x * 8 + (t >> 5);
    int c = t & 31;
    if (a >= N) return;
    float acc = rb1[c];
    const float* pr = p1 + (size_t)a * 64;
    #pragma unroll
    for (int k = 0; k < 64; ++k)
        acc = fmaf(pr[k], rw1[k * 32 + c], acc);
    float e = fast_tanh(acc) * rw2[c];
    #pragma unroll
    for (int off = 16; off > 0; off >>= 1)
        e += __shfl_down(e, off, 32);
    if (c == 0) atomicAdd(&out[abatch[a]], e + rb2[0]);
}

extern "C" void kernel_launch(void* const* d_in, const int* in_sizes, int n_in,
                              void* d_out, int out_size, void* d_ws, size_t ws_size,
                              hipStream_t stream) {
    const int*   Z         = (const int*)  d_in[0];
    const float* pair_diff = (const float*)d_in[1];
    const int*   pair_i    = (const int*)  d_in[2];
    const int*   pair_j    = (const int*)  d_in[3];
    const int*   abatch    = (const int*)  d_in[4];
    const float* embed_w   = (const float*)d_in[6];
    const float* pp_w1     = (const float*)d_in[7];
    const float* pp_b1     = (const float*)d_in[8];
    const float* pp_w2     = (const float*)d_in[9];
    const float* pp_b2     = (const float*)d_in[10];
    const float* pi_w1     = (const float*)d_in[11];
    const float* pi_b1     = (const float*)d_in[12];
    const float* pi_w2     = (const float*)d_in[13];
    const float* pi_b2     = (const float*)d_in[14];
    const float* ii_w1     = (const float*)d_in[15];
    const float* ii_w2     = (const float*)d_in[16];
    // d_in[17] = pix_w : dead w.r.t. delta_energy
    const float* ro_w1     = (const float*)d_in[18];
    const float* ro_b1     = (const float*)d_in[19];
    const float* ro_w2     = (const float*)d_in[20];
    const float* ro_b2     = (const float*)d_in[21];

    const int N = in_sizes[0];
    const int P = in_sizes[2];

    float* ws    = (float*)d_ws;
    float* basis = ws;                          // P*16
    float* p1    = basis + (size_t)P * 16;      // N*64
    float* u     = p1 + (size_t)N * 64;         // N*64
    float* v     = u + (size_t)N * 64;          // N*64
    float* wt    = v + (size_t)N * 64;          // 4*2*4096 fp32
    __bf16* w2bf = (__bf16*)(wt + 4 * 2 * 4096); // 2*65536 bf16
    __bf16* w3bf = w2bf + 2 * 65536;             // 2*4096
    __bf16* w4bf = w3bf + 2 * 4096;              // 2*4096

    float* out_f = (float*)d_out;
    (void)hipMemsetAsync(d_out, 0, (size_t)out_size * sizeof(float), stream);

    k_prep_wt<<<(4 * 2 * 4096 + 255) / 256, 256, 0, stream>>>(pp_w1, pp_w2, pi_w1, wt);
    k_prep_bf<<<(147456 + 255) / 256, 256, 0, stream>>>(pi_w2, ii_w1, ii_w2, w2bf, w3bf, w4bf);
    k_pairprep<<<(P + 255) / 256, 256, 0, stream>>>(pair_diff, basis, P);
    k_embed<<<(N * 64 + 255) / 256, 256, 0, stream>>>(Z, embed_w, p1, N);

    for (int d = 0; d < 2; ++d) {
        const float* ppw1t = wt + (0 * 2 + d) * 4096;
        const float* ppw2t = wt + (1 * 2 + d) * 4096;
        const float* pi1tt = wt + (2 * 2 + d) * 4096;
        const float* pi1tb = wt + (3 * 2 + d) * 4096;
        k_pp<<<(N + 63) / 64, 256, 0, stream>>>(p1, ppw1t, pp_b1 + d * 64, ppw2t, pp_b2 + d * 64,
                                                pi1tt, pi1tb, pi_b1 + d * 64, u, v, N);
        k_pair<<<(P + 63) / 64, 256, 0, stream>>>(u, v, pair_i, pair_j, basis,
                                                  w2bf + (size_t)d * 65536, pi_b2 + d * 1024,
                                                  w3bf + (size_t)d * 4096, w4bf + (size_t)d * 4096,
                                                  p1, P);
    }

    k_readout<<<(N + 7) / 8, 256, 0, stream>>>(p1, ro_w1, ro_b1, ro_w2, ro_b2, abatch, out_f, N);
}

// Round 4
// 248.602 us; speedup vs baseline: 2.9480x; 1.1020x over previous
//
#include <hip/hip_runtime.h>
#include <hip/hip_bf16.h>

#define PI_F 3.14159265358979323846f

typedef __bf16 bf16x8 __attribute__((ext_vector_type(8)));
typedef float  f32x4  __attribute__((ext_vector_type(4)));

#define MFMA16(a, b, c) __builtin_amdgcn_mfma_f32_16x16x32_bf16((a), (b), (c), 0, 0, 0)

__device__ __forceinline__ float fast_tanh(float x) {
    float e = __expf(2.0f * x);
    return 1.0f - 2.0f * __fdividef(1.0f, e + 1.0f);
}

// ---------------- K0: fp32 transposes for k_pp ----------------
// wt layout: [4 mats][2 depths][64 c][64 k], Bt[c][k] = W[k][c]
__global__ void k_prep_wt(const float* __restrict__ pp_w1,
                          const float* __restrict__ pp_w2,
                          const float* __restrict__ pi_w1,
                          float* __restrict__ wt) {
    int idx = blockIdx.x * blockDim.x + threadIdx.x;
    if (idx >= 4 * 2 * 4096) return;
    int k = idx & 63;
    int c = (idx >> 6) & 63;
    int d = (idx >> 12) & 1;
    int m = idx >> 13;
    float val = 0.f;
    switch (m) {
        case 0: val = pp_w1[d * 4096 + k * 64 + c]; break;
        case 1: val = pp_w2[d * 4096 + k * 64 + c]; break;
        case 2: val = pi_w1[d * 8192 + k * 64 + c]; break;          // top half
        case 3: val = pi_w1[d * 8192 + (64 + k) * 64 + c]; break;   // bottom half
    }
    wt[idx] = val;
}

// ---------------- K0b: bf16 transposed weights + b-major re-layout ----------------
// w2bf[d][n'][k] with n' = b*64 + c  = pi_w2[d][k][c*16+b]   (k<64, c<64, b<16)
// w3bf[d][n][k] = ii_w1[d][k][n]
// w4bf[d][n][k] = ii_w2[d][k][n] (first 64 of 192 cols)
// b2t[d][b*64+c] = pi_b2[d][c*16+b]
__global__ void k_prep_bf(const float* __restrict__ pi_w2,
                          const float* __restrict__ ii_w1,
                          const float* __restrict__ ii_w2,
                          const float* __restrict__ pi_b2,
                          __bf16* __restrict__ w2bf,
                          __bf16* __restrict__ w3bf,
                          __bf16* __restrict__ w4bf,
                          float* __restrict__ b2t) {
    int idx = blockIdx.x * blockDim.x + threadIdx.x;
    if (idx < 131072) {
        int d = idx >> 16, r = idx & 65535;
        int np = r >> 6, k = r & 63;
        int b = np >> 6, c = np & 63;
        w2bf[idx] = (__bf16)pi_w2[d * 65536 + k * 1024 + c * 16 + b];
    } else if (idx < 139264) {
        int tt = idx - 131072;
        int d = tt >> 12, r = tt & 4095;
        int n = r >> 6, k = r & 63;
        w3bf[tt] = (__bf16)ii_w1[d * 4096 + k * 64 + n];
    } else if (idx < 147456) {
        int tt = idx - 139264;
        int d = tt >> 12, r = tt & 4095;
        int n = r >> 6, k = r & 63;
        w4bf[tt] = (__bf16)ii_w2[d * 12288 + k * 192 + n];
    } else if (idx < 149504) {
        int tt = idx - 147456;
        int d = tt >> 10, r = tt & 1023;
        int b = r >> 6, c = r & 63;
        b2t[tt] = pi_b2[d * 1024 + c * 16 + b];
    }
}

// ---------------- K1: pair geometry -> RBF basis [P,16] ----------------
__global__ void k_pairprep(const float* __restrict__ pair_diff,
                           float* __restrict__ basis, int P) {
    int p = blockIdx.x * blockDim.x + threadIdx.x;
    if (p >= P) return;
    float x = pair_diff[3 * p + 0];
    float y = pair_diff[3 * p + 1];
    float z = pair_diff[3 * p + 2];
    float d = sqrtf(x * x + y * y + z * z + 1e-12f);
    float fc = 0.0f;
    if (d < 4.0f) fc = 0.5f * (__cosf(PI_F * d * 0.25f) + 1.0f);
    const float inv_sigma = 15.0f / 4.0f;
    float out[16];
    #pragma unroll
    for (int b = 0; b < 16; ++b) {
        float cb = (4.0f / 15.0f) * (float)b;
        float tt = (d - cb) * inv_sigma;
        out[b] = __expf(-0.5f * tt * tt) * fc;
    }
    float4* o4 = (float4*)(basis + (size_t)p * 16);
    o4[0] = make_float4(out[0], out[1], out[2], out[3]);
    o4[1] = make_float4(out[4], out[5], out[6], out[7]);
    o4[2] = make_float4(out[8], out[9], out[10], out[11]);
    o4[3] = make_float4(out[12], out[13], out[14], out[15]);
}

// ---------------- K2: embedding gather ----------------
__global__ void k_embed(const int* __restrict__ Z, const float* __restrict__ embed_w,
                        float* __restrict__ p1, int N) {
    int idx = blockIdx.x * blockDim.x + threadIdx.x;
    if (idx >= N * 64) return;
    int n = idx >> 6, c = idx & 63;
    p1[idx] = embed_w[Z[n] * 64 + c];
}

// ---------------- fp32 64x64 GEMM helper (k_pp only) ----------------
__device__ __forceinline__ void gemm64(const float (*A)[68], const float* __restrict__ Bt,
                                       int tx, int ty, float acc[4][4]) {
    #pragma unroll
    for (int i = 0; i < 4; ++i)
        #pragma unroll
        for (int j = 0; j < 4; ++j) acc[i][j] = 0.f;
    #pragma unroll 8
    for (int k = 0; k < 64; k += 2) {
        float2 bv[4];
        #pragma unroll
        for (int j = 0; j < 4; ++j)
            bv[j] = *(const float2*)(Bt + (tx + 16 * j) * 64 + k);
        #pragma unroll
        for (int i = 0; i < 4; ++i) {
            float2 av = *(const float2*)&A[ty + 16 * i][k];
            #pragma unroll
            for (int j = 0; j < 4; ++j)
                acc[i][j] = fmaf(av.x, bv[j].x, fmaf(av.y, bv[j].y, acc[i][j]));
        }
    }
}

// ---------------- K3: per-atom pp MLP + u/v precompute (fp32) ----------------
__launch_bounds__(256, 2)
__global__ void k_pp(const float* __restrict__ p1,
                     const float* __restrict__ w1t, const float* __restrict__ b1,
                     const float* __restrict__ w2t, const float* __restrict__ b2,
                     const float* __restrict__ wut, const float* __restrict__ wvt,
                     const float* __restrict__ bu,
                     float* __restrict__ u, float* __restrict__ v, int N) {
    __shared__ float sA[64][68];
    __shared__ float sH[64][68];
    int t = threadIdx.x;
    int a0 = blockIdx.x * 64;
    {
        int r = t >> 2, q = t & 3;
        int a = a0 + r;
        #pragma unroll
        for (int w = 0; w < 4; ++w) {
            int cc = q * 16 + w * 4;
            float4 val = make_float4(0.f, 0.f, 0.f, 0.f);
            if (a < N) val = *(const float4*)(p1 + (size_t)a * 64 + cc);
            *(float4*)&sA[r][cc] = val;
        }
    }
    __syncthreads();
    const int tx = t >> 4, ty = t & 15;

    float acc[4][4];
    gemm64(sA, w1t, tx, ty, acc);
    #pragma unroll
    for (int i = 0; i < 4; ++i)
        #pragma unroll
        for (int j = 0; j < 4; ++j)
            sH[ty + 16 * i][tx + 16 * j] = fast_tanh(acc[i][j] + b1[tx + 16 * j]);
    __syncthreads();
    gemm64(sH, w2t, tx, ty, acc);
    #pragma unroll
    for (int i = 0; i < 4; ++i)
        #pragma unroll
        for (int j = 0; j < 4; ++j)
            sA[ty + 16 * i][tx + 16 * j] = fast_tanh(acc[i][j] + b2[tx + 16 * j]);
    __syncthreads();

    float accU[4][4], accV[4][4];
    gemm64(sA, wut, tx, ty, accU);
    gemm64(sA, wvt, tx, ty, accV);
    #pragma unroll
    for (int i = 0; i < 4; ++i) {
        int a = a0 + ty + 16 * i;
        if (a < N) {
            #pragma unroll
            for (int j = 0; j < 4; ++j) {
                int c = tx + 16 * j;
                u[(size_t)a * 64 + c] = accU[i][j] + bu[c];
                v[(size_t)a * 64 + c] = accV[i][j];
            }
        }
    }
}

// ---------------- K4: fused pair kernel — bf16 MFMA, b-major epilogue ----------------
// S^T tiles: A = w2bf rows (n' = b*64 + c), B = g^T. Per 16-row tile all rows share one b.
// Lane (ll,lg,reg r): col=pair=pt*16+ll, row=lg*4+r => c = wv*16+lg*4+r, b = tile index.
// i1 accumulated in-register across the 16 b-tiles: no shuffles, no divergence.
__launch_bounds__(256, 4)
__global__ void k_pair(const float* __restrict__ u, const float* __restrict__ v,
                       const int* __restrict__ pair_i, const int* __restrict__ pair_j,
                       const float* __restrict__ basis,
                       const __bf16* __restrict__ w2bf, const float* __restrict__ b2t,
                       const __bf16* __restrict__ w3bf, const __bf16* __restrict__ w4bf,
                       float* __restrict__ p1, int P) {
    __shared__ __bf16 sGH[64][72];   // g [pair][k]; later reused for h [pair][o]
    __shared__ __bf16 sI1[64][72];   // i1 [pair][c]
    __shared__ float sB[64][20];     // basis [pair][16]
    __shared__ int sPi[64];

    const int t = threadIdx.x;
    const int base = blockIdx.x * 64;

    // ---- phase 1: g = tanh(u[i]+v[j]) -> bf16 LDS; basis -> LDS ----
    {
        int r = t >> 2, q = t & 3;
        int p = base + r;
        bool valid = (p < P);
        int ai = 0, aj = 0;
        if (valid) { ai = pair_i[p]; aj = pair_j[p]; }
        if (q == 0) sPi[r] = valid ? ai : -1;
        int cc = q * 16;
        bf16x8 g8a, g8b;
        f32x4 b4 = {0.f, 0.f, 0.f, 0.f};
        if (valid) {
            const f32x4* up = (const f32x4*)(u + (size_t)ai * 64 + cc);
            const f32x4* vp = (const f32x4*)(v + (size_t)aj * 64 + cc);
            f32x4 u0 = up[0], u1 = up[1], u2 = up[2], u3 = up[3];
            f32x4 v0 = vp[0], v1 = vp[1], v2 = vp[2], v3 = vp[3];
            #pragma unroll
            for (int e = 0; e < 4; ++e) {
                g8a[e]     = (__bf16)fast_tanh(u0[e] + v0[e]);
                g8a[4 + e] = (__bf16)fast_tanh(u1[e] + v1[e]);
                g8b[e]     = (__bf16)fast_tanh(u2[e] + v2[e]);
                g8b[4 + e] = (__bf16)fast_tanh(u3[e] + v3[e]);
            }
            b4 = *(const f32x4*)(basis + (size_t)p * 16 + q * 4);
        } else {
            #pragma unroll
            for (int e = 0; e < 8; ++e) { g8a[e] = (__bf16)0.f; g8b[e] = (__bf16)0.f; }
        }
        *(bf16x8*)&sGH[r][cc]     = g8a;
        *(bf16x8*)&sGH[r][cc + 8] = g8b;
        *(f32x4*)&sB[r][q * 4]    = b4;
    }
    __syncthreads();

    const int l  = t & 63;
    const int wv = t >> 6;
    const int ll = l & 15;
    const int lg = l >> 4;

    // B-frags: g^T, register-resident for the whole main loop
    bf16x8 bg[4][2];
    #pragma unroll
    for (int pt = 0; pt < 4; ++pt)
        #pragma unroll
        for (int kt = 0; kt < 2; ++kt)
            bg[pt][kt] = *(const bf16x8*)&sGH[pt * 16 + ll][kt * 32 + lg * 8];

    // ---- main loop over 16 b-tiles; wave wv owns c-quadrant [wv*16, wv*16+16) ----
    f32x4 s[4];
    {
        const f32x4 z4 = {0.f, 0.f, 0.f, 0.f};
        #pragma unroll
        for (int pt = 0; pt < 4; ++pt) s[pt] = z4;
    }
    #pragma unroll 1
    for (int b = 0; b < 16; ++b) {
        const __bf16* ar = w2bf + (size_t)(b * 64 + wv * 16 + ll) * 64 + lg * 8;
        bf16x8 a0 = *(const bf16x8*)(ar);
        bf16x8 a1 = *(const bf16x8*)(ar + 32);
        f32x4 acc[4];
        {
            const f32x4 z4 = {0.f, 0.f, 0.f, 0.f};
            #pragma unroll
            for (int pt = 0; pt < 4; ++pt) acc[pt] = z4;
        }
        #pragma unroll
        for (int pt = 0; pt < 4; ++pt) {
            acc[pt] = MFMA16(a0, bg[pt][0], acc[pt]);
            acc[pt] = MFMA16(a1, bg[pt][1], acc[pt]);
        }
        f32x4 bias = *(const f32x4*)(b2t + b * 64 + wv * 16 + lg * 4);
        #pragma unroll
        for (int pt = 0; pt < 4; ++pt) {
            float bas = sB[pt * 16 + ll][b];
            #pragma unroll
            for (int r = 0; r < 4; ++r)
                s[pt][r] = fmaf(fast_tanh(acc[pt][r] + bias[r]), bas, s[pt][r]);
        }
    }
    // write i1[p][c], c = wv*16 + lg*4 + r  (contiguous 4x bf16 per pt, all lanes active)
    #pragma unroll
    for (int pt = 0; pt < 4; ++pt) {
        __bf16 o4[4];
        #pragma unroll
        for (int r = 0; r < 4; ++r) o4[r] = (__bf16)s[pt][r];
        *(ushort2*)&sI1[pt * 16 + ll][wv * 16 + lg * 4]     = *(ushort2*)&o4[0];
        *(ushort2*)&sI1[pt * 16 + ll][wv * 16 + lg * 4 + 2] = *(ushort2*)&o4[2];
    }
    __syncthreads();

    // ---- ii GEMM1: h = tanh(i1 @ ii_w1); wave wv owns out cols [wv*16, wv*16+16) ----
    f32x4 acc2[4];
    {
        const f32x4 z4 = {0.f, 0.f, 0.f, 0.f};
        #pragma unroll
        for (int mt = 0; mt < 4; ++mt) acc2[mt] = z4;
    }
    #pragma unroll
    for (int kt = 0; kt < 2; ++kt) {
        bf16x8 bw = *(const bf16x8*)(w3bf + (size_t)(wv * 16 + ll) * 64 + kt * 32 + lg * 8);
        #pragma unroll
        for (int mt = 0; mt < 4; ++mt) {
            bf16x8 af = *(const bf16x8*)&sI1[mt * 16 + ll][kt * 32 + lg * 8];
            acc2[mt] = MFMA16(af, bw, acc2[mt]);
        }
    }
    // sGH now dead (bg is register-resident and all waves are past the barrier): reuse for h
    #pragma unroll
    for (int mt = 0; mt < 4; ++mt)
        #pragma unroll
        for (int r = 0; r < 4; ++r)
            sGH[mt * 16 + lg * 4 + r][wv * 16 + ll] = (__bf16)fast_tanh(acc2[mt][r]);
    __syncthreads();

    // ---- ii GEMM2: i1a = h @ ii_w2[:, :64]; scatter atomicAdd to p1[pair_i] ----
    f32x4 acc3[4];
    {
        const f32x4 z4 = {0.f, 0.f, 0.f, 0.f};
        #pragma unroll
        for (int mt = 0; mt < 4; ++mt) acc3[mt] = z4;
    }
    #pragma unroll
    for (int kt = 0; kt < 2; ++kt) {
        bf16x8 bw = *(const bf16x8*)(w4bf + (size_t)(wv * 16 + ll) * 64 + kt * 32 + lg * 8);
        #pragma unroll
        for (int mt = 0; mt < 4; ++mt) {
            bf16x8 af = *(const bf16x8*)&sGH[mt * 16 + ll][kt * 32 + lg * 8];
            acc3[mt] = MFMA16(af, bw, acc3[mt]);
        }
    }
    #pragma unroll
    for (int mt = 0; mt < 4; ++mt) {
        #pragma unroll
        for (int r = 0; r < 4; ++r) {
            int p = mt * 16 + lg * 4 + r;
            int ai = sPi[p];
            if (ai >= 0)
                atomicAdd(p1 + (size_t)ai * 64 + wv * 16 + ll, acc3[mt][r]);
        }
    }
}

// ---------------- K5: readout + batch segment sum ----------------
__global__ void k_readout(const float* __restrict__ p1, const float* __restrict__ rw1,
                          const float* __restrict__ rb1, const float* __restrict__ rw2,
                          const float* __restrict__ rb2, const int* __restrict__ abatch,
                          float* __restrict__ out, int N) {
    int t = threadIdx.x;
    int a = blockIdx.x * 8 + (t >> 5);
    int c = t & 31;
    if (a >= N) return;
    float acc = rb1[c];
    const float* pr = p1 + (size_t)a * 64;
    #pragma unroll
    for (int k = 0; k < 64; ++k)
        acc = fmaf(pr[k], rw1[k * 32 + c], acc);
    float e = fast_tanh(acc) * rw2[c];
    #pragma unroll
    for (int off = 16; off > 0; off >>= 1)
        e += __shfl_down(e, off, 32);
    if (c == 0) atomicAdd(&out[abatch[a]], e + rb2[0]);
}

extern "C" void kernel_launch(void* const* d_in, const int* in_sizes, int n_in,
                              void* d_out, int out_size, void* d_ws, size_t ws_size,
                              hipStream_t stream) {
    const int*   Z         = (const int*)  d_in[0];
    const float* pair_diff = (const float*)d_in[1];
    const int*   pair_i    = (const int*)  d_in[2];
    const int*   pair_j    = (const int*)  d_in[3];
    const int*   abatch    = (const int*)  d_in[4];
    const float* embed_w   = (const float*)d_in[6];
    const float* pp_w1     = (const float*)d_in[7];
    const float* pp_b1     = (const float*)d_in[8];
    const float* pp_w2     = (const float*)d_in[9];
    const float* pp_b2     = (const float*)d_in[10];
    const float* pi_w1     = (const float*)d_in[11];
    const float* pi_b1     = (const float*)d_in[12];
    const float* pi_w2     = (const float*)d_in[13];
    const float* pi_b2     = (const float*)d_in[14];
    const float* ii_w1     = (const float*)d_in[15];
    const float* ii_w2     = (const float*)d_in[16];
    // d_in[17] = pix_w : dead w.r.t. delta_energy
    const float* ro_w1     = (const float*)d_in[18];
    const float* ro_b1     = (const float*)d_in[19];
    const float* ro_w2     = (const float*)d_in[20];
    const float* ro_b2     = (const float*)d_in[21];

    const int N = in_sizes[0];
    const int P = in_sizes[2];

    float* ws    = (float*)d_ws;
    float* basis = ws;                           // P*16
    float* p1    = basis + (size_t)P * 16;       // N*64
    float* u     = p1 + (size_t)N * 64;          // N*64
    float* v     = u + (size_t)N * 64;           // N*64
    float* wt    = v + (size_t)N * 64;           // 4*2*4096 fp32
    float* b2t   = wt + 4 * 2 * 4096;            // 2*1024 fp32
    __bf16* w2bf = (__bf16*)(b2t + 2 * 1024);    // 2*65536 bf16
    __bf16* w3bf = w2bf + 2 * 65536;             // 2*4096
    __bf16* w4bf = w3bf + 2 * 4096;              // 2*4096

    float* out_f = (float*)d_out;
    (void)hipMemsetAsync(d_out, 0, (size_t)out_size * sizeof(float), stream);

    k_prep_wt<<<(4 * 2 * 4096 + 255) / 256, 256, 0, stream>>>(pp_w1, pp_w2, pi_w1, wt);
    k_prep_bf<<<(149504 + 255) / 256, 256, 0, stream>>>(pi_w2, ii_w1, ii_w2, pi_b2,
                                                        w2bf, w3bf, w4bf, b2t);
    k_pairprep<<<(P + 255) / 256, 256, 0, stream>>>(pair_diff, basis, P);
    k_embed<<<(N * 64 + 255) / 256, 256, 0, stream>>>(Z, embed_w, p1, N);

    for (int d = 0; d < 2; ++d) {
        const float* ppw1t = wt + (0 * 2 + d) * 4096;
        const float* ppw2t = wt + (1 * 2 + d) * 4096;
        const float* pi1tt = wt + (2 * 2 + d) * 4096;
        const float* pi1tb = wt + (3 * 2 + d) * 4096;
        k_pp<<<(N + 63) / 64, 256, 0, stream>>>(p1, ppw1t, pp_b1 + d * 64, ppw2t, pp_b2 + d * 64,
                                                pi1tt, pi1tb, pi_b1 + d * 64, u, v, N);
        k_pair<<<(P + 63) / 64, 256, 0, stream>>>(u, v, pair_i, pair_j, basis,
                                                  w2bf + (size_t)d * 65536, b2t + d * 1024,
                                                  w3bf + (size_t)d * 4096, w4bf + (size_t)d * 4096,
                                                  p1, P);
    }

    k_readout<<<(N + 7) / 8, 256, 0, stream>>>(p1, ro_w1, ro_b1, ro_w2, ro_b2, abatch, out_f, N);
}